// Round 11
// baseline (163.371 us; speedup 1.0000x reference)
//
#include <hip/hip_runtime.h>

// CRF-RNN mean-field, separable filters, ONE kernel per iteration via
// z-major TRANSPOSED plane layout. 6 dispatches total.
// Grid 24(z) x 24(y) x 16(x), N=9216, C=2, 5 iterations.
//
// Math (= R9, absmax ~0): Ks(th3) separable; Kb = S160*E_i E_j*exp(I3_i I3_j)
// Taylor NT=5. Pairs: 0=(q0,q1) th3; 1+t=(Pt q0, Pt q1) th160; norm pairs
// N0..N2 = (P0,P1),(P2,P3),(P4,0) th160 filtered once.
//
// Transposed layout PT[p][yx][z] (float2): a thread owning column yx reads
// all 24 z of a plane as 12 contiguous float4 -- so kernel k_it (block z,p)
// can redundantly recompute the pointwise UPDATE for all 24 slices of its
// columns from Phi_{it-1}, form pair p, z-conv in registers, xy-conv in LDS,
// and store Phi_it[p] transposed. One kernel boundary per iteration.
//
// Lessons: R3/R10: persistent-kernel cross-block sync loses both ways
// (fence=bulk L2 wb/inv; sc1=uncached LLC trips) -- kernel boundaries with
// normal cached loads are the cheap coherence. R7: no long-stride load
// storms -- all plane reads here are dense float4 runs.

#define DD 24
#define HH 24
#define WW 16
#define SLICE 384
#define NPTS 9216
#define NT 5
#define LOG2E 1.4426950408889634f
#define K3L   (LOG2E / 18.0f)
#define K160L (LOG2E / 51200.0f)
#define EXP2  __builtin_amdgcn_exp2f

static __device__ __forceinline__ int iabs(int a) { return a < 0 ? -a : a; }

// load 8 consecutive float2 (one z-chunk of one column) as 4 float4
static __device__ __forceinline__ void ld8(const float2* p, float2* v) {
    const float4* q = (const float4*)p;
#pragma unroll
    for (int h = 0; h < 4; ++h) {
        float4 f = q[h];
        v[2 * h] = make_float2(f.x, f.y);
        v[2 * h + 1] = make_float2(f.z, f.w);
    }
}

// xy separable conv of one float2 pair (block-uniform, syncs)
static __device__ void xyconv(float2 v, int y, int x, const float* gk,
                              float2 (*sA)[WW + 1], float2 (*sB)[WW + 1],
                              float2* ov) {
    sA[y][x] = v;
    __syncthreads();
    float a0 = 0.f, a1 = 0.f;
#pragma unroll
    for (int xp = 0; xp < WW; ++xp) {
        float w = gk[iabs(x - xp)];
        float2 vv = sA[y][xp];
        a0 = fmaf(w, vv.x, a0);
        a1 = fmaf(w, vv.y, a1);
    }
    sB[y][x] = make_float2(a0, a1);
    __syncthreads();
    float b0 = 0.f, b1 = 0.f;
#pragma unroll
    for (int yp = 0; yp < HH; ++yp) {
        float w = gk[iabs(y - yp)];
        float2 vv = sB[yp][x];
        b0 = fmaf(w, vv.x, b0);
        b1 = fmaf(w, vv.y, b1);
    }
    *ov = make_float2(b0, b1);
    __syncthreads();
}

// ---- k0: Phi_0 = filter(pairs(u)) + norm planes + uT/rgbT. grid (24,9) --
__global__ __launch_bounds__(SLICE)
void k0(const float2* __restrict__ u2, const float* __restrict__ rgb,
        float2* __restrict__ PT, float2* __restrict__ PN,
        float2* __restrict__ uT, float* __restrict__ rgbT) {
    __shared__ float g3[32];
    __shared__ float g160[32];
    __shared__ float2 sA[HH][WW + 1];
    __shared__ float2 sB[HH][WW + 1];
    const int z = blockIdx.x, p = blockIdx.y, t = threadIdx.x;
    const int y = t >> 4, x = t & 15;

    if (t < DD) {
        g3[t] = EXP2(-(float)(t * t) * K3L);
        g160[t] = EXP2(-(float)(t * t) * K160L);
    }
    __syncthreads();
    const float* wz = (p == 0) ? g3 : g160;

    float a0 = 0.f, a1 = 0.f;
#pragma unroll 8
    for (int zp = 0; zp < DD; ++zp) {
        float w = wz[iabs(z - zp)];
        float I3 = rgb[zp * SLICE + t] * (1.f / 3.f);
        float E = EXP2(-0.5f * LOG2E * I3 * I3);
        float F0, F1;
        if (p < 6) {
            float2 uu = u2[zp * SLICE + t];
            float P = E;
            for (int s = 1; s < p; ++s) P *= I3;     // P = E*I3^(p-1)
            if (p == 0) { F0 = uu.x; F1 = uu.y; }
            else { F0 = P * uu.x; F1 = P * uu.y; }
        } else {
            float P0 = E, P1 = E * I3, P2 = P1 * I3, P3 = P2 * I3, P4 = P3 * I3;
            if (p == 6) { F0 = P0; F1 = P1; }
            else if (p == 7) { F0 = P2; F1 = P3; }
            else { F0 = P4; F1 = 0.f; }
        }
        a0 = fmaf(w, F0, a0);
        a1 = fmaf(w, F1, a1);
    }

    float2 ov;
    xyconv(make_float2(a0, a1), y, x, wz, sA, sB, &ov);
    if (p < 6) PT[p * NPTS + t * DD + z] = ov;
    else       PN[(p - 6) * NPTS + t * DD + z] = ov;

    if (p == 0) {   // stash transposed u / rgb for later kernels
        uT[t * DD + z] = u2[z * SLICE + t];
        rgbT[t * DD + z] = rgb[z * SLICE + t];
    }
}

// ---- k_it: Phi_it from Phi_{it-1}. grid (24,6) --------------------------
__global__ __launch_bounds__(SLICE)
void k_it(const float2* __restrict__ Psrc, float2* __restrict__ Pdst,
          const float2* __restrict__ PN,
          const float2* __restrict__ uT, const float* __restrict__ rgbT,
          const float* __restrict__ sw, const float* __restrict__ bw,
          const float* __restrict__ compat) {
    __shared__ float g3[32];
    __shared__ float g160[32];
    __shared__ float szr[DD];
    __shared__ float2 sA[HH][WW + 1];
    __shared__ float2 sB[HH][WW + 1];
    const int z = blockIdx.x, p = blockIdx.y, t = threadIdx.x;
    const int y = t >> 4, x = t & 15;

    if (t < DD) {
        g3[t] = EXP2(-(float)(t * t) * K3L);
        g160[t] = EXP2(-(float)(t * t) * K160L);
    }
    __syncthreads();
    if (t < DD) {
        float s = 0.f;
        for (int zp = 0; zp < DD; ++zp) s += g3[iabs(t - zp)];
        szr[t] = 1.0f / s;
    }
    float sx = 0.f, sy = 0.f;
#pragma unroll
    for (int xp = 0; xp < WW; ++xp) sx += g3[iabs(x - xp)];
#pragma unroll
    for (int yp = 0; yp < HH; ++yp) sy += g3[iabs(y - yp)];
    const float rxy = 1.0f / (sx * sy);
    __syncthreads();

    const float sw0 = sw[0], sw1 = sw[1];
    const float bw0 = bw[0], bw1 = bw[1];
    const float c00 = compat[0], c01 = compat[1];
    const float c10 = compat[2], c11 = compat[3];
    const float* wz = (p == 0) ? g3 : g160;
    const int col = t * DD;

    float za0 = 0.f, za1 = 0.f;
    for (int c = 0; c < 3; ++c) {
        const int zb = c * 8;
        // intensity factors for this z-chunk of the column
        float I3[8], E[8];
        {
            const float4* rq = (const float4*)(rgbT + col + zb);
            float4 r0 = rq[0], r1 = rq[1];
            float rr[8] = {r0.x, r0.y, r0.z, r0.w, r1.x, r1.y, r1.z, r1.w};
#pragma unroll
            for (int j = 0; j < 8; ++j) {
                I3[j] = rr[j] * (1.f / 3.f);
                E[j] = EXP2(-0.5f * LOG2E * I3[j] * I3[j]);
            }
        }
        float2 uu[8];
        ld8(uT + col + zb, uu);
        float2 sp[8];
        ld8(Psrc + 0 * NPTS + col + zb, sp);

        float b0[8], b1[8], cur[8];
#pragma unroll
        for (int j = 0; j < 8; ++j) { b0[j] = 0.f; b1[j] = 0.f; cur[j] = E[j]; }
        {
            float2 v[8];
            ld8(Psrc + 1 * NPTS + col + zb, v);
#pragma unroll
            for (int j = 0; j < 8; ++j) {
                b0[j] = fmaf(cur[j], v[j].x, b0[j]);
                b1[j] = fmaf(cur[j], v[j].y, b1[j]);
            }
            const float kf[4] = {1.f, 0.5f, 1.f / 3.f, 0.25f};
            for (int k = 1; k < NT; ++k) {
                ld8(Psrc + (1 + k) * NPTS + col + zb, v);
#pragma unroll
                for (int j = 0; j < 8; ++j) {
                    cur[j] *= I3[j] * kf[k - 1];
                    b0[j] = fmaf(cur[j], v[j].x, b0[j]);
                    b1[j] = fmaf(cur[j], v[j].y, b1[j]);
                }
            }
        }
        float nb[8];
        {
            float2 n0[8], n1[8], n2[8];
            ld8(PN + 0 * NPTS + col + zb, n0);
            ld8(PN + 1 * NPTS + col + zb, n1);
            ld8(PN + 2 * NPTS + col + zb, n2);
#pragma unroll
            for (int j = 0; j < 8; ++j) {
                float c2 = E[j];
                float s = c2 * n0[j].x;
                c2 *= I3[j];                 s = fmaf(c2, n0[j].y, s);
                c2 *= I3[j] * 0.5f;          s = fmaf(c2, n1[j].x, s);
                c2 *= I3[j] * (1.f / 3.f);   s = fmaf(c2, n1[j].y, s);
                c2 *= I3[j] * 0.25f;         s = fmaf(c2, n2[j].x, s);
                nb[j] = s;
            }
        }
        // pair power P = E*I3^(p-1) (p uniform)
        float Pp[8];
#pragma unroll
        for (int j = 0; j < 8; ++j) Pp[j] = E[j];
        for (int s = 1; s < p; ++s)
#pragma unroll
            for (int j = 0; j < 8; ++j) Pp[j] *= I3[j];

#pragma unroll
        for (int j = 0; j < 8; ++j) {
            int zp = zb + j;
            float rnb = 1.0f / nb[j];
            float bb0 = b0[j] * rnb;
            float bb1 = b1[j] * rnb;
            float rs = rxy * szr[zp];
            float ss0 = sp[j].x * rs;
            float ss1 = sp[j].y * rs;
            float m0 = ss0 * sw0 + bb0 * bw0;
            float m1 = ss1 * sw1 + bb1 * bw1;
            float q0 = uu[j].x - fmaf(c00, m0, c01 * m1);
            float q1 = uu[j].y - fmaf(c10, m0, c11 * m1);
            float F0, F1;
            if (p == 0) { F0 = q0; F1 = q1; }
            else { F0 = Pp[j] * q0; F1 = Pp[j] * q1; }
            float w = wz[iabs(z - zp)];
            za0 = fmaf(w, F0, za0);
            za1 = fmaf(w, F1, za1);
        }
    }

    float2 ov;
    xyconv(make_float2(za0, za1), y, x, wz, sA, sB, &ov);
    Pdst[p * NPTS + col + z] = ov;
}

// ---- k_out: final update from Phi_4 -> out. grid 36 x 256 ---------------
__global__ __launch_bounds__(256)
void k_out(const float2* __restrict__ Psrc, const float2* __restrict__ PN,
           const float2* __restrict__ uT, const float* __restrict__ rgbT,
           const float* __restrict__ sw, const float* __restrict__ bw,
           const float* __restrict__ compat, float2* __restrict__ out) {
    __shared__ float g3[32];
    const int t = threadIdx.x;
    const int j = blockIdx.x * 256 + t;
    if (t < DD) g3[t] = EXP2(-(float)(t * t) * K3L);
    __syncthreads();

    const int yx = j / DD;
    const int z = j - yx * DD;
    const int y = yx >> 4, x = yx & 15;

    float sx = 0.f, sy = 0.f, sz = 0.f;
#pragma unroll
    for (int xp = 0; xp < WW; ++xp) sx += g3[iabs(x - xp)];
#pragma unroll
    for (int yp = 0; yp < HH; ++yp) sy += g3[iabs(y - yp)];
#pragma unroll
    for (int zp = 0; zp < DD; ++zp) sz += g3[iabs(z - zp)];
    const float inv_ns = 1.0f / (sx * sy * sz);

    const float I3 = rgbT[j] * (1.f / 3.f);
    const float E = EXP2(-0.5f * LOG2E * I3 * I3);

    float2 spv = Psrc[0 * NPTS + j];
    float b0 = 0.f, b1 = 0.f, cur = E;
    {
        float2 v = Psrc[1 * NPTS + j];
        b0 = fmaf(cur, v.x, b0); b1 = fmaf(cur, v.y, b1);
        const float kf[4] = {1.f, 0.5f, 1.f / 3.f, 0.25f};
#pragma unroll
        for (int k = 1; k < NT; ++k) {
            v = Psrc[(1 + k) * NPTS + j];
            cur *= I3 * kf[k - 1];
            b0 = fmaf(cur, v.x, b0); b1 = fmaf(cur, v.y, b1);
        }
    }
    float2 n0 = PN[0 * NPTS + j], n1 = PN[1 * NPTS + j], n2 = PN[2 * NPTS + j];
    float c2 = E;
    float nb = c2 * n0.x;
    c2 *= I3;               nb = fmaf(c2, n0.y, nb);
    c2 *= I3 * 0.5f;        nb = fmaf(c2, n1.x, nb);
    c2 *= I3 * (1.f / 3.f); nb = fmaf(c2, n1.y, nb);
    c2 *= I3 * 0.25f;       nb = fmaf(c2, n2.x, nb);

    float rnb = 1.0f / nb;
    float bb0 = b0 * rnb, bb1 = b1 * rnb;
    float ss0 = spv.x * inv_ns, ss1 = spv.y * inv_ns;
    float m0 = ss0 * sw[0] + bb0 * bw[0];
    float m1 = ss1 * sw[1] + bb1 * bw[1];
    float2 uu = uT[j];
    float q0 = uu.x - fmaf(compat[0], m0, compat[1] * m1);
    float q1 = uu.y - fmaf(compat[2], m0, compat[3] * m1);
    out[z * SLICE + yx] = make_float2(q0, q1);
}

extern "C" void kernel_launch(void* const* d_in, const int* in_sizes, int n_in,
                              void* d_out, int out_size, void* d_ws, size_t ws_size,
                              hipStream_t stream) {
    const float2* u2     = (const float2*)d_in[0];
    const float*  rgb    = (const float*)d_in[1];
    const float*  sw     = (const float*)d_in[2];
    const float*  bw     = (const float*)d_in[3];
    const float*  compat = (const float*)d_in[4];
    float2* out = (float2*)d_out;

    float2* ws2  = (float2*)d_ws;
    float2* PA   = ws2;                 // 6*NPTS
    float2* PB   = ws2 + 6 * NPTS;      // 6*NPTS
    float2* PN   = ws2 + 12 * NPTS;     // 3*NPTS
    float2* uT   = ws2 + 15 * NPTS;     // NPTS
    float*  rgbT = (float*)(ws2 + 16 * NPTS);  // NPTS floats

    k0<<<dim3(DD, 9), SLICE, 0, stream>>>(u2, rgb, PA, PN, uT, rgbT);

    const float2* src = PA;
    float2* dst = PB;
    for (int it = 1; it <= 4; ++it) {
        k_it<<<dim3(DD, 6), SLICE, 0, stream>>>(src, dst, PN, uT, rgbT,
                                                sw, bw, compat);
        const float2* ns = dst;
        dst = (float2*)src;
        src = ns;
    }
    k_out<<<NPTS / 256, 256, 0, stream>>>(src, PN, uT, rgbT,
                                          sw, bw, compat, out);
}

// Round 12
// 102.478 us; speedup vs baseline: 1.5942x; 1.5942x over previous
//
#include <hip/hip_runtime.h>

// CRF-RNN mean-field, separable filters, 10 dispatches.
// Grid 24(z) x 24(y) x 16(x), N=9216, C=2, 5 iterations.
//
// Math (= R9, absmax 0.0): Ks(th3) separable exact; Kb = S160*E_i E_j*
// exp(I3_i I3_j), Taylor NT=5 (err ~1e-7). Pairs: 0=(q0,q1) th3;
// 1+t=(Pt q0, Pt q1) th160. Norm pairs (P0,P1),(P2,P3),(P4,0) th160.
//
// Structure: k0 (grid 24x9) z-convs pair/norm fields DIRECTLY from u/rgb
// (fields are pointwise in u,rgb; separable axes commute) then xy-convs in
// LDS -> fully filtered Phi0 + norm planes + normS, ONE kernel. Each
// iteration: kA (pointwise update at own slice + xy-conv of pair p -> T)
// then kB (z-conv of 6 pairs -> Phi). Final: pointwise k_out.
//
// Lessons: R3/R10: persistent-kernel sync loses both ways (fence = bulk L2
// wb/inv; sc1 = uncached LLC trips) -- kernel boundaries + cached loads are
// the cheap coherence. R7/R11: one-kernel-per-iter forces >=24x read
// redundancy (tens of MB) -- 2 cheap boundaries/iter with non-redundant
// reads wins. R6/R8: wide grids; marginal dispatch ~1.4us + ~3us exec/ramp.

#define DD 24
#define HH 24
#define WW 16
#define SLICE 384
#define NPTS 9216
#define NT 5
#define LOG2E 1.4426950408889634f
#define K3L   (LOG2E / 18.0f)
#define K160L (LOG2E / 51200.0f)
#define EXP2  __builtin_amdgcn_exp2f

static __device__ __forceinline__ int iabs(int a) { return a < 0 ? -a : a; }

// xy separable conv of one float2 pair (block-uniform, syncs)
static __device__ void xyconv(float2 v, int y, int x, const float* gk,
                              float2 (*sA)[WW + 1], float2 (*sB)[WW + 1],
                              float2* ov) {
    sA[y][x] = v;
    __syncthreads();
    float a0 = 0.f, a1 = 0.f;
#pragma unroll
    for (int xp = 0; xp < WW; ++xp) {
        float w = gk[iabs(x - xp)];
        float2 vv = sA[y][xp];
        a0 = fmaf(w, vv.x, a0);
        a1 = fmaf(w, vv.y, a1);
    }
    sB[y][x] = make_float2(a0, a1);
    __syncthreads();
    float b0 = 0.f, b1 = 0.f;
#pragma unroll
    for (int yp = 0; yp < HH; ++yp) {
        float w = gk[iabs(y - yp)];
        float2 vv = sB[yp][x];
        b0 = fmaf(w, vv.x, b0);
        b1 = fmaf(w, vv.y, b1);
    }
    *ov = make_float2(b0, b1);
    __syncthreads();
}

// ---- k0: Phi0 (6 pairs) + 3 norm planes + normS, z-conv direct from u --
__global__ __launch_bounds__(SLICE)
void k0(const float2* __restrict__ u2, const float* __restrict__ rgb,
        float2* __restrict__ Phi, float2* __restrict__ PhiN,
        float* __restrict__ normS) {
    __shared__ float gk[32];
    __shared__ float2 sA[HH][WW + 1];
    __shared__ float2 sB[HH][WW + 1];
    const int z = blockIdx.x, p = blockIdx.y, t = threadIdx.x;
    const int y = t >> 4, x = t & 15;
    const int i = z * SLICE + t;

    const float kk = (p == 0) ? K3L : K160L;
    if (t < DD) gk[t] = EXP2(-(float)(t * t) * kk);
    __syncthreads();

    // z-conv of this pair's field, computed pointwise from u/rgb (108 KB,
    // L2-shared by all 216 blocks)
    float a0 = 0.f, a1 = 0.f;
#pragma unroll 8
    for (int zp = 0; zp < DD; ++zp) {
        float w = gk[iabs(z - zp)];
        float I3 = rgb[zp * SLICE + t] * (1.f / 3.f);
        float E = EXP2(-0.5f * LOG2E * I3 * I3);
        float F0, F1;
        if (p < 6) {
            float2 uu = u2[zp * SLICE + t];
            float P = E;
            for (int s = 1; s < p; ++s) P *= I3;     // P = E*I3^(p-1)
            if (p == 0) { F0 = uu.x; F1 = uu.y; }
            else { F0 = P * uu.x; F1 = P * uu.y; }
        } else {
            float P0 = E, P1 = E * I3, P2 = P1 * I3, P3 = P2 * I3, P4 = P3 * I3;
            if (p == 6) { F0 = P0; F1 = P1; }
            else if (p == 7) { F0 = P2; F1 = P3; }
            else { F0 = P4; F1 = 0.f; }
        }
        a0 = fmaf(w, F0, a0);
        a1 = fmaf(w, F1, a1);
    }

    float2 ov;
    xyconv(make_float2(a0, a1), y, x, gk, sA, sB, &ov);
    if (p < 6) Phi[p * NPTS + i] = ov;
    else       PhiN[(p - 6) * NPTS + i] = ov;

    if (p == 0) {   // inverse spatial normalization (gk == g3 here)
        float sx = 0.f, sy = 0.f, sz = 0.f;
#pragma unroll
        for (int xp = 0; xp < WW; ++xp) sx += gk[iabs(x - xp)];
#pragma unroll
        for (int yp = 0; yp < HH; ++yp) sy += gk[iabs(y - yp)];
#pragma unroll
        for (int zp = 0; zp < DD; ++zp) sz += gk[iabs(z - zp)];
        normS[i] = 1.0f / (sx * sy * sz);
    }
}

// ---- shared pointwise update --------------------------------------------
static __device__ __forceinline__ void mf_update(
        const float2 zp_[6], const float* Pt, float inv_ns, float inv_nb,
        const float* sw, const float* bw, const float* compat,
        const float2 uu, float* q0o, float* q1o) {
    const float invf[NT] = {1.f, 1.f, 0.5f, 1.f / 6.f, 1.f / 24.f};
    float b0 = 0.f, b1 = 0.f;
#pragma unroll
    for (int k = 0; k < NT; ++k) {
        float w = Pt[k] * invf[k];
        b0 = fmaf(w, zp_[1 + k].x, b0);
        b1 = fmaf(w, zp_[1 + k].y, b1);
    }
    b0 *= inv_nb;
    b1 *= inv_nb;
    float s0 = zp_[0].x * inv_ns;
    float s1 = zp_[0].y * inv_ns;
    float m0 = s0 * sw[0] + b0 * bw[0];
    float m1 = s1 * sw[1] + b1 * bw[1];
    float p0 = fmaf(compat[0], m0, compat[1] * m1);
    float p1 = fmaf(compat[2], m0, compat[3] * m1);
    *q0o = uu.x - p0;
    *q1o = uu.y - p1;
}

// ---- kA: update (pointwise on Phi) + xy-conv of pair p -> T. grid (24,6) -
__global__ __launch_bounds__(SLICE)
void kA(const float2* __restrict__ Phi, const float2* __restrict__ PhiN,
        const float* __restrict__ rgb, const float2* __restrict__ u2,
        const float* __restrict__ sw, const float* __restrict__ bw,
        const float* __restrict__ compat,
        const float* __restrict__ normS, float* __restrict__ normB,
        float2* __restrict__ T, int first) {
    __shared__ float gk[32];
    __shared__ float2 sA[HH][WW + 1];
    __shared__ float2 sB[HH][WW + 1];
    const int z = blockIdx.x, p = blockIdx.y, t = threadIdx.x;
    const int y = t >> 4, x = t & 15;
    const int i = z * SLICE + t;

    const float kk = (p == 0) ? K3L : K160L;
    if (t < DD) gk[t] = EXP2(-(float)(t * t) * kk);

    float2 zp_[6];
#pragma unroll
    for (int k = 0; k < 6; ++k) zp_[k] = Phi[k * NPTS + i];

    const float I3 = rgb[i] * (1.f / 3.f);
    float Pt[NT];
    Pt[0] = EXP2(-0.5f * LOG2E * I3 * I3);
#pragma unroll
    for (int k = 1; k < NT; ++k) Pt[k] = Pt[k - 1] * I3;

    float inv_nb;
    if (first) {
        float2 n0 = PhiN[0 * NPTS + i];
        float2 n1 = PhiN[1 * NPTS + i];
        float2 n2 = PhiN[2 * NPTS + i];
        float nb = Pt[0] * n0.x + Pt[1] * n0.y + 0.5f * Pt[2] * n1.x
                 + (1.f / 6.f) * Pt[3] * n1.y + (1.f / 24.f) * Pt[4] * n2.x;
        if (p == 0) normB[i] = nb;
        inv_nb = 1.0f / nb;
    } else {
        inv_nb = 1.0f / normB[i];
    }

    float q0, q1;
    mf_update(zp_, Pt, normS[i], inv_nb, sw, bw, compat, u2[i], &q0, &q1);

    float2 v;
    if (p == 0) v = make_float2(q0, q1);
    else { float P = Pt[p - 1]; v = make_float2(P * q0, P * q1); }

    float2 ov;
    xyconv(v, y, x, gk, sA, sB, &ov);
    T[p * NPTS + i] = ov;
}

// ---- kB: z-conv of pair p, no LDS. grid (24,6) --------------------------
__global__ __launch_bounds__(SLICE)
void kB(const float2* __restrict__ T, float2* __restrict__ Phi) {
    const int z = blockIdx.x, p = blockIdx.y, t = threadIdx.x;
    const float kk = (p == 0) ? K3L : K160L;
    float a0 = 0.f, a1 = 0.f;
    const float2* src = T + p * NPTS + t;
#pragma unroll 6
    for (int zp = 0; zp < DD; ++zp) {
        int d = z - zp;
        float w = EXP2(-(float)(d * d) * kk);
        float2 v = src[zp * SLICE];
        a0 = fmaf(w, v.x, a0);
        a1 = fmaf(w, v.y, a1);
    }
    Phi[p * NPTS + z * SLICE + t] = make_float2(a0, a1);
}

// ---- k_out: final pointwise update -> out. grid 36 x 256 ----------------
__global__ __launch_bounds__(256)
void k_out(const float2* __restrict__ Phi, const float* __restrict__ rgb,
           const float2* __restrict__ u2,
           const float* __restrict__ sw, const float* __restrict__ bw,
           const float* __restrict__ compat,
           const float* __restrict__ normS, const float* __restrict__ normB,
           float2* __restrict__ out) {
    const int i = blockIdx.x * 256 + threadIdx.x;

    float2 zp_[6];
#pragma unroll
    for (int k = 0; k < 6; ++k) zp_[k] = Phi[k * NPTS + i];

    const float I3 = rgb[i] * (1.f / 3.f);
    float Pt[NT];
    Pt[0] = EXP2(-0.5f * LOG2E * I3 * I3);
#pragma unroll
    for (int k = 1; k < NT; ++k) Pt[k] = Pt[k - 1] * I3;

    float q0, q1;
    mf_update(zp_, Pt, normS[i], 1.0f / normB[i], sw, bw, compat,
              u2[i], &q0, &q1);
    out[i] = make_float2(q0, q1);
}

extern "C" void kernel_launch(void* const* d_in, const int* in_sizes, int n_in,
                              void* d_out, int out_size, void* d_ws, size_t ws_size,
                              hipStream_t stream) {
    const float2* u2     = (const float2*)d_in[0];
    const float*  rgb    = (const float*)d_in[1];
    const float*  sw     = (const float*)d_in[2];
    const float*  bw     = (const float*)d_in[3];
    const float*  compat = (const float*)d_in[4];
    float2* out = (float2*)d_out;

    float2* ws2   = (float2*)d_ws;
    float2* PhiA  = ws2;                  // 6*NPTS
    float2* PhiB  = ws2 + 6 * NPTS;       // 6*NPTS
    float2* PhiN  = ws2 + 12 * NPTS;      // 3*NPTS
    float2* T     = ws2 + 15 * NPTS;      // 6*NPTS
    float*  normS = (float*)(ws2 + 21 * NPTS);   // NPTS
    float*  normB = normS + NPTS;                 // NPTS

    k0<<<dim3(DD, 9), SLICE, 0, stream>>>(u2, rgb, PhiA, PhiN, normS);

    const float2* cur = PhiA;
    float2* nxt = PhiB;
    for (int it = 0; it < 4; ++it) {
        kA<<<dim3(DD, 6), SLICE, 0, stream>>>(cur, PhiN, rgb, u2, sw, bw,
                                              compat, normS, normB, T,
                                              it == 0 ? 1 : 0);
        kB<<<dim3(DD, 6), SLICE, 0, stream>>>(T, nxt);
        const float2* ns = nxt;
        nxt = (float2*)cur;
        cur = ns;
    }
    k_out<<<NPTS / 256, 256, 0, stream>>>(cur, rgb, u2, sw, bw, compat,
                                          normS, normB, out);
}

// Round 13
// 96.936 us; speedup vs baseline: 1.6853x; 1.0572x over previous
//
#include <hip/hip_runtime.h>

// CRF-RNN mean-field, separable filters, field-PAIRED planes, 11 dispatches.
// Grid 24(z) x 24(y) x 16(x), N=9216, C=2, 5 iterations.
// == Best-measured variant (R9: 97.6 us). Restored as final. ==
//
// Ks (theta=3) = Gz (x) Gy (x) Gx  -- exact separable 1-D convs.
// Kb = S160 * E_i E_j * exp(I3_i*I3_j), Taylor NT=5 (err ~1e-7).
// 6 iter PAIRS: pair0 = (q0,q1) theta=3; pair(1+t) = (P_t q0, P_t q1) th=160.
// 3 norm pairs (6..8): (P0,P1),(P2,P3),(P4,0) th=160, filtered once.
//
// Structure/iter: k_zconv (tmp2 -> zout2, one pair per block, no LDS) then
// k_xyupd (zout2 -> pointwise update (redundant per pair-block) -> xy-conv of
// pair p -> tmp2). Final iter: k_zconv + pointwise k_final.
//
// Session lessons (measured):
//  - R3/R10: persistent-kernel sync loses both ways (threadfence = bulk L2
//    wb/inv ~19us/barrier; relaxed sc1 = uncached LLC trips, FETCH 10.9 MB).
//    Kernel boundaries + normal cached loads are the cheap coherence on
//    gfx950 (per-XCD L2, CP handles wb/inv efficiently at boundary).
//  - R7/R11: one-kernel-per-iteration forces >=24x read redundancy (long-
//    stride load storms, 82 / 20 us per kernel). 2 thin boundaries/iter with
//    non-redundant reads wins.
//  - R6/R8/R9: wide grids (>=144 blocks); marginal dispatch ~1.4 us; exec
//    ~3.5 us/kernel is ramp/cold-L2/instruction overhead, minimized via raw
//    v_exp_f32, float2 planes, no LDS in zconv/final, precomputed normS.
//  - Plateau 97.6-103.8 us across 10/11-dispatch variants; ~45 us of total
//    is harness fill+restore. This is the launch-bound floor.

#define DD 24
#define HH 24
#define WW 16
#define SLICE 384
#define NPTS 9216
#define NT 5
#define NPAIR 6
#define NPTOT 9
#define LOG2E 1.4426950408889634f
#define K3L   (LOG2E / 18.0f)
#define K160L (LOG2E / 51200.0f)
#define EXP2  __builtin_amdgcn_exp2f

static __device__ __forceinline__ int iabs(int a) { return a < 0 ? -a : a; }

// ---- pre: xy conv of 9 pairs from q=u. grid (DD, 9) ---------------------
__global__ __launch_bounds__(SLICE)
void k_pre(const float2* __restrict__ u2, const float* __restrict__ rgb,
           float2* __restrict__ tmp2, float* __restrict__ normS) {
    __shared__ float gk[32];
    __shared__ float2 sA[HH][WW + 1];
    __shared__ float2 sB[HH][WW + 1];
    const int z = blockIdx.x, p = blockIdx.y, t = threadIdx.x;
    const int y = t >> 4, x = t & 15;
    const int i = z * SLICE + t;

    const float kk = (p == 0) ? K3L : K160L;
    if (t < DD) gk[t] = EXP2(-(float)(t * t) * kk);

    const float I3 = rgb[i] * (1.f / 3.f);
    float Pt[NT];
    Pt[0] = EXP2(-0.5f * LOG2E * I3 * I3);
#pragma unroll
    for (int k = 1; k < NT; ++k) Pt[k] = Pt[k - 1] * I3;

    float2 v;
    if (p == 0) {
        v = u2[i];
    } else if (p < NPAIR) {
        float2 q = u2[i];
        float P = Pt[p - 1];
        v = make_float2(P * q.x, P * q.y);
    } else {
        int j = p - NPAIR;
        v = make_float2(Pt[2 * j], (j < 2) ? Pt[2 * j + 1] : 0.f);
    }
    sA[y][x] = v;
    __syncthreads();

    float a0 = 0.f, a1 = 0.f;
#pragma unroll
    for (int xp = 0; xp < WW; ++xp) {
        float w = gk[iabs(x - xp)];
        float2 vv = sA[y][xp];
        a0 = fmaf(w, vv.x, a0);
        a1 = fmaf(w, vv.y, a1);
    }
    sB[y][x] = make_float2(a0, a1);
    __syncthreads();
    float b0 = 0.f, b1 = 0.f;
#pragma unroll
    for (int yp = 0; yp < HH; ++yp) {
        float w = gk[iabs(y - yp)];
        float2 vv = sB[yp][x];
        b0 = fmaf(w, vv.x, b0);
        b1 = fmaf(w, vv.y, b1);
    }
    tmp2[p * NPTS + i] = make_float2(b0, b1);

    if (p == 0) {
        // inverse spatial normalization, stored once (gk == g3 here)
        float sx = 0.f, sy = 0.f, sz = 0.f;
#pragma unroll
        for (int xp = 0; xp < WW; ++xp) sx += gk[iabs(x - xp)];
#pragma unroll
        for (int yp = 0; yp < HH; ++yp) sy += gk[iabs(y - yp)];
#pragma unroll
        for (int zp = 0; zp < DD; ++zp) sz += gk[iabs(z - zp)];
        normS[i] = 1.0f / (sx * sy * sz);
    }
}

// ---- z conv, ONE pair per block, no LDS. grid (DD, np) ------------------
__global__ __launch_bounds__(SLICE)
void k_zconv(const float2* __restrict__ tmp2, float2* __restrict__ zout2) {
    const int z = blockIdx.x, p = blockIdx.y, t = threadIdx.x;
    const float kk = (p == 0) ? K3L : K160L;
    float acc0 = 0.f, acc1 = 0.f;
    const float2* src = tmp2 + p * NPTS + t;
#pragma unroll 6
    for (int zp = 0; zp < DD; ++zp) {
        int d = z - zp;
        float w = EXP2(-(float)(d * d) * kk);
        float2 v = src[zp * SLICE];
        acc0 = fmaf(w, v.x, acc0);
        acc1 = fmaf(w, v.y, acc1);
    }
    zout2[p * NPTS + z * SLICE + t] = make_float2(acc0, acc1);
}

// ---- shared pointwise update ------------------------------------------
static __device__ __forceinline__ void mf_update(
        const float2 zp_[NPAIR], const float* Pt, float inv_ns, float inv_nb,
        const float* sw, const float* bw, const float* compat,
        const float2 uu, float* q0o, float* q1o) {
    const float invf[NT] = {1.f, 1.f, 0.5f, 1.f / 6.f, 1.f / 24.f};
    float b0 = 0.f, b1 = 0.f;
#pragma unroll
    for (int k = 0; k < NT; ++k) {
        float w = Pt[k] * invf[k];
        b0 = fmaf(w, zp_[1 + k].x, b0);
        b1 = fmaf(w, zp_[1 + k].y, b1);
    }
    b0 *= inv_nb;
    b1 *= inv_nb;
    float s0 = zp_[0].x * inv_ns;
    float s1 = zp_[0].y * inv_ns;
    float m0 = s0 * sw[0] + b0 * bw[0];
    float m1 = s1 * sw[1] + b1 * bw[1];
    float p0 = fmaf(compat[0], m0, compat[1] * m1);
    float p1 = fmaf(compat[2], m0, compat[3] * m1);
    *q0o = uu.x - p0;
    *q1o = uu.y - p1;
}

// ---- fused update + xy conv of pair p. grid (DD, 6) ---------------------
__global__ __launch_bounds__(SLICE)
void k_xyupd(const float2* __restrict__ zout2, const float* __restrict__ rgb,
             const float2* __restrict__ u2,
             const float* __restrict__ sw, const float* __restrict__ bw,
             const float* __restrict__ compat,
             const float* __restrict__ normS, float* __restrict__ normB,
             float2* __restrict__ tmp2, int it) {
    __shared__ float gk[32];
    __shared__ float2 sA[HH][WW + 1];
    __shared__ float2 sB[HH][WW + 1];
    const int z = blockIdx.x, p = blockIdx.y, t = threadIdx.x;
    const int y = t >> 4, x = t & 15;
    const int i = z * SLICE + t;

    const float kk = (p == 0) ? K3L : K160L;
    if (t < DD) gk[t] = EXP2(-(float)(t * t) * kk);

    float2 zp_[NPAIR];
#pragma unroll
    for (int k = 0; k < NPAIR; ++k) zp_[k] = zout2[k * NPTS + i];

    const float I3 = rgb[i] * (1.f / 3.f);
    float Pt[NT];
    Pt[0] = EXP2(-0.5f * LOG2E * I3 * I3);
#pragma unroll
    for (int k = 1; k < NT; ++k) Pt[k] = Pt[k - 1] * I3;

    float inv_nb;
    if (it == 0) {
        float2 n0 = zout2[6 * NPTS + i];
        float2 n1 = zout2[7 * NPTS + i];
        float2 n2 = zout2[8 * NPTS + i];
        float nb = Pt[0] * n0.x + Pt[1] * n0.y + 0.5f * Pt[2] * n1.x
                 + (1.f / 6.f) * Pt[3] * n1.y + (1.f / 24.f) * Pt[4] * n2.x;
        if (p == 0) normB[i] = nb;
        inv_nb = 1.0f / nb;
    } else {
        inv_nb = 1.0f / normB[i];
    }

    float q0, q1;
    mf_update(zp_, Pt, normS[i], inv_nb, sw, bw, compat, u2[i], &q0, &q1);

    float2 v;
    if (p == 0) v = make_float2(q0, q1);
    else { float P = Pt[p - 1]; v = make_float2(P * q0, P * q1); }

    sA[y][x] = v;
    __syncthreads();
    float a0 = 0.f, a1 = 0.f;
#pragma unroll
    for (int xp = 0; xp < WW; ++xp) {
        float w = gk[iabs(x - xp)];
        float2 vv = sA[y][xp];
        a0 = fmaf(w, vv.x, a0);
        a1 = fmaf(w, vv.y, a1);
    }
    sB[y][x] = make_float2(a0, a1);
    __syncthreads();
    float b0 = 0.f, b1 = 0.f;
#pragma unroll
    for (int yp = 0; yp < HH; ++yp) {
        float w = gk[iabs(y - yp)];
        float2 vv = sB[yp][x];
        b0 = fmaf(w, vv.x, b0);
        b1 = fmaf(w, vv.y, b1);
    }
    tmp2[p * NPTS + i] = make_float2(b0, b1);
}

// ---- final pointwise update -> out. grid 36 x 256, no LDS ---------------
__global__ __launch_bounds__(256)
void k_final(const float2* __restrict__ zout2, const float* __restrict__ rgb,
             const float2* __restrict__ u2,
             const float* __restrict__ sw, const float* __restrict__ bw,
             const float* __restrict__ compat,
             const float* __restrict__ normS, const float* __restrict__ normB,
             float2* __restrict__ out) {
    const int i = blockIdx.x * 256 + threadIdx.x;

    float2 zp_[NPAIR];
#pragma unroll
    for (int k = 0; k < NPAIR; ++k) zp_[k] = zout2[k * NPTS + i];

    const float I3 = rgb[i] * (1.f / 3.f);
    float Pt[NT];
    Pt[0] = EXP2(-0.5f * LOG2E * I3 * I3);
#pragma unroll
    for (int k = 1; k < NT; ++k) Pt[k] = Pt[k - 1] * I3;

    float q0, q1;
    mf_update(zp_, Pt, normS[i], 1.0f / normB[i], sw, bw, compat,
              u2[i], &q0, &q1);
    out[i] = make_float2(q0, q1);
}

extern "C" void kernel_launch(void* const* d_in, const int* in_sizes, int n_in,
                              void* d_out, int out_size, void* d_ws, size_t ws_size,
                              hipStream_t stream) {
    const float2* u2     = (const float2*)d_in[0];
    const float*  rgb    = (const float*)d_in[1];
    const float*  sw     = (const float*)d_in[2];
    const float*  bw     = (const float*)d_in[3];
    const float*  compat = (const float*)d_in[4];
    float2* out = (float2*)d_out;

    float2* ws2   = (float2*)d_ws;
    float2* tmp2  = ws2;                        // NPTOT*NPTS float2
    float2* zout2 = ws2 + NPTOT * NPTS;         // NPTOT*NPTS float2
    float*  normS = (float*)(ws2 + 2 * NPTOT * NPTS);   // NPTS
    float*  normB = normS + NPTS;                        // NPTS

    k_pre<<<dim3(DD, NPTOT), SLICE, 0, stream>>>(u2, rgb, tmp2, normS);

    for (int it = 0; it < 5; ++it) {
        k_zconv<<<dim3(DD, it == 0 ? NPTOT : NPAIR), SLICE, 0, stream>>>(tmp2, zout2);
        if (it < 4)
            k_xyupd<<<dim3(DD, NPAIR), SLICE, 0, stream>>>(zout2, rgb, u2, sw, bw,
                                                           compat, normS, normB,
                                                           tmp2, it);
        else
            k_final<<<NPTS / 256, 256, 0, stream>>>(zout2, rgb, u2, sw, bw,
                                                    compat, normS, normB, out);
    }
}